// Round 1
// 870.806 us; speedup vs baseline: 1.1766x; 1.1766x over previous
//
#include <hip/hip_runtime.h>
#include <hip/hip_bf16.h>

#define B_ 2
#define L_ 4800
#define S_ 4800
#define C_ 256
#define NT_ 75                      // 4800 / 64 tiles per side
#define BL_ (B_ * L_)               // 9600
#define BS_ (B_ * S_)               // 9600
#define BLS ((size_t)B_ * L_ * S_)

constexpr float kLOG2E = 1.4426950408889634f;

typedef __bf16 bf16x8 __attribute__((ext_vector_type(8)));
typedef float f32x4 __attribute__((ext_vector_type(4)));

static __device__ __forceinline__ f32x4 mfma16(bf16x8 a, bf16x8 b, f32x4 c) {
    return __builtin_amdgcn_mfma_f32_16x16x32_bf16(a, b, c, 0, 0, 0);
}

// load 8 contiguous fp32, round-to-nearest-even convert to bf16x8
static __device__ __forceinline__ bf16x8 load_cvt8(const float* __restrict__ p) {
    float4 a = *(const float4*)p;
    float4 b = *(const float4*)(p + 4);
    bf16x8 r;
    r[0] = (__bf16)a.x; r[1] = (__bf16)a.y; r[2] = (__bf16)a.z; r[3] = (__bf16)a.w;
    r[4] = (__bf16)b.x; r[5] = (__bf16)b.y; r[6] = (__bf16)b.z; r[7] = (__bf16)b.w;
    return r;
}

// ---------------- K1: projection f = (x @ W^T + bias) / 16, bf16 out ----------------
// UNCHANGED from passing version (bitwise-identical f0/f1).
__global__ __launch_bounds__(256) void proj_kernel(
    const float* __restrict__ x0, const float* __restrict__ x1,
    const float* __restrict__ W, const float* __restrict__ bias,
    __hip_bfloat16* __restrict__ y0, __hip_bfloat16* __restrict__ y1) {
    const float* __restrict__ x = (blockIdx.z == 0) ? x0 : x1;
    __hip_bfloat16* __restrict__ y = (blockIdx.z == 0) ? y0 : y1;

    int lane = threadIdx.x & 63, wid = threadIdx.x >> 6;
    int m = lane & 15, q = lane >> 4;
    int r0 = blockIdx.x * 64 + wid * 16;
    int c0 = blockIdx.y * 16;

    f32x4 acc = {0.f, 0.f, 0.f, 0.f};
    for (int kk = 0; kk < 8; ++kk) {
        bf16x8 a = load_cvt8(x + (size_t)(r0 + m) * C_ + kk * 32 + q * 8);
        bf16x8 b = load_cvt8(W + (size_t)(c0 + m) * C_ + kk * 32 + q * 8);
        acc = mfma16(a, b, acc);
    }
    float bv = bias[c0 + m];
#pragma unroll
    for (int i = 0; i < 4; ++i) {
        int row = q * 4 + i;  // C/D mapping: col = lane&15, row = (lane>>4)*4 + i
        y[(size_t)(r0 + row) * C_ + c0 + m] = __float2bfloat16((acc[i] + bv) * 0.0625f);
    }
}

// ---------------- shared 64x64 sim tile (per-wave 32x32, 2x2 frags) ----------------
// Identical MFMA dependence chain in both passes => bitwise-identical acc.
static __device__ __forceinline__ void sim_tile(
    const __hip_bfloat16* __restrict__ A, const __hip_bfloat16* __restrict__ Bp,
    int r0, int c0, int mi, int q, f32x4 acc[2][2]) {
#pragma unroll
    for (int kk = 0; kk < 8; ++kk) {
        int ko = kk * 32 + q * 8;
        bf16x8 a0 = *(const bf16x8*)(A + (size_t)(r0 + mi) * C_ + ko);
        bf16x8 a1 = *(const bf16x8*)(A + (size_t)(r0 + 16 + mi) * C_ + ko);
        bf16x8 b0 = *(const bf16x8*)(Bp + (size_t)(c0 + mi) * C_ + ko);
        bf16x8 b1 = *(const bf16x8*)(Bp + (size_t)(c0 + 16 + mi) * C_ + ko);
        acc[0][0] = mfma16(a0, b0, acc[0][0]);
        acc[0][1] = mfma16(a0, b1, acc[0][1]);
        acc[1][0] = mfma16(a1, b0, acc[1][0]);
        acc[1][1] = mfma16(a1, b1, acc[1][1]);
    }
}

// ---------------- K2: GEMM + per-tile stats (NO sim write) ----------------
// grid (75, 75, 2), block 256. Per 64x64 tile: row partial {max, sum-exp} over its
// 64 cols and col partial {max, sum-exp} over its 64 rows. No max-subtraction
// (|sim| <= ~5, exp2 range-safe in fp32) => partials merge with plain max / plain add.
__global__ __launch_bounds__(256) void simstat_kernel(
    const __hip_bfloat16* __restrict__ f0, const __hip_bfloat16* __restrict__ f1,
    float* __restrict__ rowPM, float* __restrict__ rowPZ,
    float* __restrict__ colPM, float* __restrict__ colPZ) {
    int b = blockIdx.z;
    int lane = threadIdx.x & 63, wid = threadIdx.x >> 6;
    int wm = wid & 1, wn = wid >> 1;
    int mi = lane & 15, q = lane >> 4;
    int r0 = blockIdx.x * 64 + wm * 32;
    int c0 = blockIdx.y * 64 + wn * 32;

    const __hip_bfloat16* __restrict__ A = f0 + (size_t)b * L_ * C_;
    const __hip_bfloat16* __restrict__ Bp = f1 + (size_t)b * S_ * C_;

    f32x4 acc[2][2] = {};
    sim_tile(A, Bp, r0, c0, mi, q, acc);

    // v and e (one exp per element)
    float v[2][2][4], e[2][2][4];
#pragma unroll
    for (int tm = 0; tm < 2; ++tm)
#pragma unroll
        for (int tn = 0; tn < 2; ++tn)
#pragma unroll
            for (int i = 0; i < 4; ++i) {
                float x = acc[tm][tn][i] * 10.0f;
                v[tm][tn][i] = x;
                e[tm][tn][i] = exp2f(x * kLOG2E);
            }

    // row partials: rows (tm,i) lane-local across tn, reduce over mi (lanes xor 1,2,4,8)
    float rm8[2][4], rz8[2][4];
#pragma unroll
    for (int tm = 0; tm < 2; ++tm)
#pragma unroll
        for (int i = 0; i < 4; ++i) {
            float m = fmaxf(v[tm][0][i], v[tm][1][i]);
            float z = e[tm][0][i] + e[tm][1][i];
#pragma unroll
            for (int d = 1; d < 16; d <<= 1) {
                m = fmaxf(m, __shfl_xor(m, d));
                z += __shfl_xor(z, d);
            }
            rm8[tm][i] = m; rz8[tm][i] = z;
        }

    // col partials: cols (tn) lane-local across (tm,i), reduce over q (lanes xor 16,32)
    float cm2[2], cz2[2];
#pragma unroll
    for (int tn = 0; tn < 2; ++tn) {
        float m = -3.0e38f, z = 0.f;
#pragma unroll
        for (int tm = 0; tm < 2; ++tm)
#pragma unroll
            for (int i = 0; i < 4; ++i) {
                m = fmaxf(m, v[tm][tn][i]);
                z += e[tm][tn][i];
            }
#pragma unroll
        for (int d = 16; d < 64; d <<= 1) {
            m = fmaxf(m, __shfl_xor(m, d));
            z += __shfl_xor(z, d);
        }
        cm2[tn] = m; cz2[tn] = z;
    }

    // combine the two col-halves (wn) per row and two row-halves (wm) per col via LDS
    __shared__ float lRM[2][64], lRZ[2][64], lCM[2][64], lCZ[2][64];
    if (mi == 0) {
#pragma unroll
        for (int tm = 0; tm < 2; ++tm)
#pragma unroll
            for (int i = 0; i < 4; ++i) {
                int rl = wm * 32 + tm * 16 + q * 4 + i;
                lRM[wn][rl] = rm8[tm][i];
                lRZ[wn][rl] = rz8[tm][i];
            }
    }
    if (q == 0) {
#pragma unroll
        for (int tn = 0; tn < 2; ++tn) {
            int cl = wn * 32 + tn * 16 + mi;
            lCM[wm][cl] = cm2[tn];
            lCZ[wm][cl] = cz2[tn];
        }
    }
    __syncthreads();

    int t = threadIdx.x;
    if (t < 64) {
        float m = fmaxf(lRM[0][t], lRM[1][t]);
        float z = lRZ[0][t] + lRZ[1][t];
        size_t o = (size_t)blockIdx.y * BL_ + (size_t)b * L_ + blockIdx.x * 64 + t;
        rowPM[o] = m; rowPZ[o] = z;
    } else if (t < 128) {
        int c = t - 64;
        float m = fmaxf(lCM[0][c], lCM[1][c]);
        float z = lCZ[0][c] + lCZ[1][c];
        size_t o = (size_t)blockIdx.x * BS_ + (size_t)b * S_ + blockIdx.y * 64 + c;
        colPM[o] = m; colPZ[o] = z;
    }
}

// ---------------- K3: reduce 75 partials; reciprocals; border masks ----------------
// grid 75 blocks x 256 = 19200 threads: [0,9600) rows, [9600,19200) cols.
__global__ __launch_bounds__(256) void stats_reduce_kernel(
    const float* __restrict__ rowPM, const float* __restrict__ rowPZ,
    const float* __restrict__ colPM, const float* __restrict__ colPZ,
    const int* __restrict__ ph0, const int* __restrict__ pw0,
    const int* __restrict__ ph1, const int* __restrict__ pw1,
    float* __restrict__ rowM, float* __restrict__ rowRZ, float* __restrict__ oklA,
    float* __restrict__ colM, float* __restrict__ colRZ, float* __restrict__ oksA) {
    int idx = blockIdx.x * 256 + threadIdx.x;
    if (idx < BL_) {
        float m = -3.0e38f, z = 0.f;
        for (int j = 0; j < NT_; ++j) {
            m = fmaxf(m, rowPM[(size_t)j * BL_ + idx]);
            z += rowPZ[(size_t)j * BL_ + idx];
        }
        rowM[idx] = m;
        rowRZ[idx] = 1.0f / z;
        int l = idx % L_;
        int h0 = ph0[0], w0 = pw0[0];
        int i0 = l / w0, j0 = l - i0 * w0;
        oklA[idx] = ((i0 >= 2) & (i0 < h0 - 2) & (j0 >= 2) & (j0 < w0 - 2)) ? 1.f : 0.f;
    } else if (idx < BL_ + BS_) {
        int c = idx - BL_;
        float m = -3.0e38f, z = 0.f;
        for (int j = 0; j < NT_; ++j) {
            m = fmaxf(m, colPM[(size_t)j * BS_ + c]);
            z += colPZ[(size_t)j * BS_ + c];
        }
        colM[c] = m;
        colRZ[c] = 1.0f / z;
        int s = c % S_;
        int h1 = ph1[0], w1 = pw1[0];
        int i1 = s / w1, j1 = s - i1 * w1;
        oksA[c] = ((i1 >= 2) & (i1 < h1 - 2) & (j1 >= 2) & (j1 < w1 - 2)) ? 1.f : 0.f;
    }
}

// ---------------- K4: recompute tile + write conf0/conf1/mconf directly ----------------
// grid (75, 75, 2), block 256. One exp per element, multiply by precomputed 1/z.
__global__ __launch_bounds__(256) void final_kernel(
    const __hip_bfloat16* __restrict__ f0, const __hip_bfloat16* __restrict__ f1,
    const float* __restrict__ rowM, const float* __restrict__ rowRZ, const float* __restrict__ oklA,
    const float* __restrict__ colM, const float* __restrict__ colRZ, const float* __restrict__ oksA,
    float* __restrict__ out) {
    int b = blockIdx.z;
    int lane = threadIdx.x & 63, wid = threadIdx.x >> 6;
    int wm = wid & 1, wn = wid >> 1;
    int mi = lane & 15, q = lane >> 4;
    int r0 = blockIdx.x * 64 + wm * 32;
    int c0 = blockIdx.y * 64 + wn * 32;

    // stage per-tile row/col stats into LDS (issue before the GEMM; barrier after)
    __shared__ float sRM[64], sRZ[64], sOkl[64], sCM[64], sCRZ[64], sOks[64];
    int t = threadIdx.x;
    if (t < 64) {
        int r = b * L_ + blockIdx.x * 64 + t;
        sRM[t] = rowM[r]; sRZ[t] = rowRZ[r]; sOkl[t] = oklA[r];
    } else if (t < 128) {
        int c = b * S_ + blockIdx.y * 64 + (t - 64);
        sCM[t - 64] = colM[c]; sCRZ[t - 64] = colRZ[c]; sOks[t - 64] = oksA[c];
    }

    const __hip_bfloat16* __restrict__ A = f0 + (size_t)b * L_ * C_;
    const __hip_bfloat16* __restrict__ Bp = f1 + (size_t)b * S_ * C_;
    f32x4 acc[2][2] = {};
    sim_tile(A, Bp, r0, c0, mi, q, acc);

    __syncthreads();

#pragma unroll
    for (int tm = 0; tm < 2; ++tm)
#pragma unroll
        for (int tn = 0; tn < 2; ++tn)
#pragma unroll
            for (int i = 0; i < 4; ++i) {
                int rl = wm * 32 + tm * 16 + q * 4 + i;
                int cl = wn * 32 + tn * 16 + mi;
                float v = acc[tm][tn][i] * 10.0f;
                float e = exp2f(v * kLOG2E);
                float c0v = e * sRZ[rl];
                float c1v = e * sCRZ[cl];
                bool mk = ((c0v > 0.2f) & (v == sRM[rl])) | ((c1v > 0.2f) & (v == sCM[cl]));
                float mc = mk ? fmaxf(c0v, c1v) * sOkl[rl] * sOks[cl] : 0.f;
                size_t o = ((size_t)(b * L_ + blockIdx.x * 64 + rl)) * S_ + blockIdx.y * 64 + cl;
                __builtin_nontemporal_store(c0v, &out[o]);
                __builtin_nontemporal_store(c1v, &out[o + BLS]);
                __builtin_nontemporal_store(mc, &out[o + 2 * BLS]);
            }
}

extern "C" void kernel_launch(void* const* d_in, const int* in_sizes, int n_in,
                              void* d_out, int out_size, void* d_ws, size_t ws_size,
                              hipStream_t stream) {
    const float* feat0 = (const float*)d_in[0];
    const float* feat1 = (const float*)d_in[1];
    const float* W = (const float*)d_in[2];
    const float* bias = (const float*)d_in[3];
    const int* ph0 = (const int*)d_in[4];
    const int* pw0 = (const int*)d_in[5];
    const int* ph1 = (const int*)d_in[6];
    const int* pw1 = (const int*)d_in[7];
    float* out = (float*)d_out;

    char* ws = (char*)d_ws;
    size_t off = 0;
    auto alloc = [&](size_t bytes) { char* p = ws + off; off = (off + bytes + 255) & ~(size_t)255; return p; };
    __hip_bfloat16* f0 = (__hip_bfloat16*)alloc((size_t)B_ * L_ * C_ * 2);
    __hip_bfloat16* f1 = (__hip_bfloat16*)alloc((size_t)B_ * S_ * C_ * 2);
    float* rowPM = (float*)alloc((size_t)NT_ * BL_ * 4);
    float* rowPZ = (float*)alloc((size_t)NT_ * BL_ * 4);
    float* colPM = (float*)alloc((size_t)NT_ * BS_ * 4);
    float* colPZ = (float*)alloc((size_t)NT_ * BS_ * 4);
    float* rowM = (float*)alloc((size_t)BL_ * 4);
    float* rowRZ = (float*)alloc((size_t)BL_ * 4);
    float* oklA = (float*)alloc((size_t)BL_ * 4);
    float* colM = (float*)alloc((size_t)BS_ * 4);
    float* colRZ = (float*)alloc((size_t)BS_ * 4);
    float* oksA = (float*)alloc((size_t)BS_ * 4);
    (void)ws_size; (void)in_sizes; (void)n_in; (void)out_size;

    proj_kernel<<<dim3(150, 16, 2), 256, 0, stream>>>(feat0, feat1, W, bias, f0, f1);
    simstat_kernel<<<dim3(NT_, NT_, B_), 256, 0, stream>>>(f0, f1, rowPM, rowPZ, colPM, colPZ);
    stats_reduce_kernel<<<dim3(75), 256, 0, stream>>>(rowPM, rowPZ, colPM, colPZ,
                                                      ph0, pw0, ph1, pw1,
                                                      rowM, rowRZ, oklA, colM, colRZ, oksA);
    final_kernel<<<dim3(NT_, NT_, B_), 256, 0, stream>>>(f0, f1, rowM, rowRZ, oklA,
                                                         colM, colRZ, oksA, out);
}

// Round 4
// 786.036 us; speedup vs baseline: 1.3035x; 1.1078x over previous
//
#include <hip/hip_runtime.h>
#include <hip/hip_bf16.h>

#define B_ 2
#define L_ 4800
#define S_ 4800
#define C_ 256
#define NT2_ 50                     // 4800 / 96 tiles per side
#define BL_ (B_ * L_)               // 9600
#define BS_ (B_ * S_)               // 9600
#define BLS ((size_t)B_ * L_ * S_)

constexpr float kLOG2E = 1.4426950408889634f;

typedef __bf16 bf16x8 __attribute__((ext_vector_type(8)));
typedef float f32x4 __attribute__((ext_vector_type(4)));

static __device__ __forceinline__ f32x4 mfma16(bf16x8 a, bf16x8 b, f32x4 c) {
    return __builtin_amdgcn_mfma_f32_16x16x32_bf16(a, b, c, 0, 0, 0);
}

// load 8 contiguous fp32, round-to-nearest-even convert to bf16x8
static __device__ __forceinline__ bf16x8 load_cvt8(const float* __restrict__ p) {
    float4 a = *(const float4*)p;
    float4 b = *(const float4*)(p + 4);
    bf16x8 r;
    r[0] = (__bf16)a.x; r[1] = (__bf16)a.y; r[2] = (__bf16)a.z; r[3] = (__bf16)a.w;
    r[4] = (__bf16)b.x; r[5] = (__bf16)b.y; r[6] = (__bf16)b.z; r[7] = (__bf16)b.w;
    return r;
}

// ---------------- K1: projection f = (x @ W^T + bias) / 16, bf16 out ----------------
// UNCHANGED from passing version.
__global__ __launch_bounds__(256) void proj_kernel(
    const float* __restrict__ x0, const float* __restrict__ x1,
    const float* __restrict__ W, const float* __restrict__ bias,
    __hip_bfloat16* __restrict__ y0, __hip_bfloat16* __restrict__ y1) {
    const float* __restrict__ x = (blockIdx.z == 0) ? x0 : x1;
    __hip_bfloat16* __restrict__ y = (blockIdx.z == 0) ? y0 : y1;

    int lane = threadIdx.x & 63, wid = threadIdx.x >> 6;
    int m = lane & 15, q = lane >> 4;
    int r0 = blockIdx.x * 64 + wid * 16;
    int c0 = blockIdx.y * 16;

    f32x4 acc = {0.f, 0.f, 0.f, 0.f};
    for (int kk = 0; kk < 8; ++kk) {
        bf16x8 a = load_cvt8(x + (size_t)(r0 + m) * C_ + kk * 32 + q * 8);
        bf16x8 b = load_cvt8(W + (size_t)(c0 + m) * C_ + kk * 32 + q * 8);
        acc = mfma16(a, b, acc);
    }
    float bv = bias[c0 + m];
#pragma unroll
    for (int i = 0; i < 4; ++i) {
        int row = q * 4 + i;  // C/D mapping: col = lane&15, row = (lane>>4)*4 + i
        y[(size_t)(r0 + row) * C_ + c0 + m] = __float2bfloat16((acc[i] + bv) * 0.0625f);
    }
}

// ---------------- K2: 96x96-tile GEMM + sim write (fp32) + per-tile stats ----------------
// grid (50, 50, 2), block 256 = 4 waves in 2x2, each wave 48x48 = 3x3 frags of 16x16x32.
// No max-subtraction (|sim| <= ~5, exp2 range-safe in fp32) => partials merge with
// plain max / plain add in K3. v is written to sim so K4 reads identical bits.
__global__ __launch_bounds__(256) void simstat_kernel(
    const __hip_bfloat16* __restrict__ f0, const __hip_bfloat16* __restrict__ f1,
    float* __restrict__ sim,
    float* __restrict__ rowPM, float* __restrict__ rowPZ,
    float* __restrict__ colPM, float* __restrict__ colPZ) {
    int b = blockIdx.z;
    int lane = threadIdx.x & 63, wid = threadIdx.x >> 6;
    int wm = wid & 1, wn = wid >> 1;
    int mi = lane & 15, q = lane >> 4;
    int r0 = blockIdx.x * 96 + wm * 48;
    int c0 = blockIdx.y * 96 + wn * 48;

    const __hip_bfloat16* __restrict__ A = f0 + (size_t)b * L_ * C_;
    const __hip_bfloat16* __restrict__ Bp = f1 + (size_t)b * S_ * C_;

    f32x4 acc[3][3] = {};
#pragma unroll
    for (int kk = 0; kk < 8; ++kk) {
        int ko = kk * 32 + q * 8;
        bf16x8 af[3], bf[3];
#pragma unroll
        for (int m = 0; m < 3; ++m)
            af[m] = *(const bf16x8*)(A + (size_t)(r0 + m * 16 + mi) * C_ + ko);
#pragma unroll
        for (int n = 0; n < 3; ++n)
            bf[n] = *(const bf16x8*)(Bp + (size_t)(c0 + n * 16 + mi) * C_ + ko);
#pragma unroll
        for (int m = 0; m < 3; ++m)
#pragma unroll
            for (int n = 0; n < 3; ++n)
                acc[m][n] = mfma16(af[m], bf[n], acc[m][n]);
    }

    // v = acc*10 and e = exp(v), one exp per element
    float v[3][3][4], e[3][3][4];
#pragma unroll
    for (int m = 0; m < 3; ++m)
#pragma unroll
        for (int n = 0; n < 3; ++n)
#pragma unroll
            for (int i = 0; i < 4; ++i) {
                float x = acc[m][n][i] * 10.0f;
                v[m][n][i] = x;
                e[m][n][i] = exp2f(x * kLOG2E);
            }

    // materialize sim (fp32): per (m,n,i) a wave writes 4 rows x 64B segments
    float* __restrict__ simb = sim + (size_t)b * L_ * S_;
#pragma unroll
    for (int m = 0; m < 3; ++m)
#pragma unroll
        for (int n = 0; n < 3; ++n)
#pragma unroll
            for (int i = 0; i < 4; ++i) {
                size_t o = (size_t)(r0 + m * 16 + q * 4 + i) * S_ + c0 + n * 16 + mi;
                __builtin_nontemporal_store(v[m][n][i], &simb[o]);
            }

    // row partials: row (m,i) lane-local across n; reduce over mi (xor 1,2,4,8)
    float rm[3][4], rz[3][4];
#pragma unroll
    for (int m = 0; m < 3; ++m)
#pragma unroll
        for (int i = 0; i < 4; ++i) {
            float mx = fmaxf(fmaxf(v[m][0][i], v[m][1][i]), v[m][2][i]);
            float zz = e[m][0][i] + e[m][1][i] + e[m][2][i];
#pragma unroll
            for (int d = 1; d < 16; d <<= 1) {
                mx = fmaxf(mx, __shfl_xor(mx, d));
                zz += __shfl_xor(zz, d);
            }
            rm[m][i] = mx; rz[m][i] = zz;
        }

    // col partials: col (n,mi) lane-local across (m,i); reduce over q (xor 16,32)
    float cm[3], cz[3];
#pragma unroll
    for (int n = 0; n < 3; ++n) {
        float mx = -3.0e38f, zz = 0.f;
#pragma unroll
        for (int m = 0; m < 3; ++m)
#pragma unroll
            for (int i = 0; i < 4; ++i) {
                mx = fmaxf(mx, v[m][n][i]);
                zz += e[m][n][i];
            }
#pragma unroll
        for (int d = 16; d < 64; d <<= 1) {
            mx = fmaxf(mx, __shfl_xor(mx, d));
            zz += __shfl_xor(zz, d);
        }
        cm[n] = mx; cz[n] = zz;
    }

    // combine the two col-halves (wn) per row and two row-halves (wm) per col via LDS
    __shared__ float lRM[2][96], lRZ[2][96], lCM[2][96], lCZ[2][96];
    if (mi == 0) {
#pragma unroll
        for (int m = 0; m < 3; ++m)
#pragma unroll
            for (int i = 0; i < 4; ++i) {
                int rl = wm * 48 + m * 16 + q * 4 + i;
                lRM[wn][rl] = rm[m][i];
                lRZ[wn][rl] = rz[m][i];
            }
    }
    if (q == 0) {
#pragma unroll
        for (int n = 0; n < 3; ++n) {
            int cl = wn * 48 + n * 16 + mi;
            lCM[wm][cl] = cm[n];
            lCZ[wm][cl] = cz[n];
        }
    }
    __syncthreads();

    int t = threadIdx.x;
    if (t < 96) {
        float m = fmaxf(lRM[0][t], lRM[1][t]);
        float z = lRZ[0][t] + lRZ[1][t];
        size_t o = (size_t)blockIdx.y * BL_ + (size_t)b * L_ + blockIdx.x * 96 + t;
        rowPM[o] = m; rowPZ[o] = z;
    } else if (t < 192) {
        int c = t - 96;
        float m = fmaxf(lCM[0][c], lCM[1][c]);
        float z = lCZ[0][c] + lCZ[1][c];
        size_t o = (size_t)blockIdx.x * BS_ + (size_t)b * S_ + blockIdx.y * 96 + c;
        colPM[o] = m; colPZ[o] = z;
    }
}

// ---------------- K3: reduce 50 partials; reciprocals; border masks ----------------
// grid 75 blocks x 256 = 19200 threads: [0,9600) rows, [9600,19200) cols.
__global__ __launch_bounds__(256) void stats_reduce_kernel(
    const float* __restrict__ rowPM, const float* __restrict__ rowPZ,
    const float* __restrict__ colPM, const float* __restrict__ colPZ,
    const int* __restrict__ ph0, const int* __restrict__ pw0,
    const int* __restrict__ ph1, const int* __restrict__ pw1,
    float* __restrict__ rowM, float* __restrict__ rowRZ, float* __restrict__ oklA,
    float* __restrict__ colM, float* __restrict__ colRZ, float* __restrict__ oksA) {
    int idx = blockIdx.x * 256 + threadIdx.x;
    if (idx < BL_) {
        float m = -3.0e38f, z = 0.f;
        for (int j = 0; j < NT2_; ++j) {
            m = fmaxf(m, rowPM[(size_t)j * BL_ + idx]);
            z += rowPZ[(size_t)j * BL_ + idx];
        }
        rowM[idx] = m;
        rowRZ[idx] = 1.0f / z;
        int l = idx % L_;
        int h0 = ph0[0], w0 = pw0[0];
        int i0 = l / w0, j0 = l - i0 * w0;
        oklA[idx] = ((i0 >= 2) & (i0 < h0 - 2) & (j0 >= 2) & (j0 < w0 - 2)) ? 1.f : 0.f;
    } else if (idx < BL_ + BS_) {
        int c = idx - BL_;
        float m = -3.0e38f, z = 0.f;
        for (int j = 0; j < NT2_; ++j) {
            m = fmaxf(m, colPM[(size_t)j * BS_ + c]);
            z += colPZ[(size_t)j * BS_ + c];
        }
        colM[c] = m;
        colRZ[c] = 1.0f / z;
        int s = c % S_;
        int h1 = ph1[0], w1 = pw1[0];
        int i1 = s / w1, j1 = s - i1 * w1;
        oksA[c] = ((i1 >= 2) & (i1 < h1 - 2) & (j1 >= 2) & (j1 < w1 - 2)) ? 1.f : 0.f;
    }
}

// ---------------- K4: pure streaming final. grid (5, 9600), block 256 ----------------
// Each thread: one float4 of one sim row -> 3 coalesced float4 nontemporal stores.
__global__ __launch_bounds__(256) void final_kernel(
    const float* __restrict__ sim,
    const float* __restrict__ rowM, const float* __restrict__ rowRZ, const float* __restrict__ oklA,
    const float* __restrict__ colM, const float* __restrict__ colRZ, const float* __restrict__ oksA,
    float* __restrict__ out) {
    int s4 = blockIdx.x * 256 + threadIdx.x;   // float4 index within a row
    if (s4 >= S_ / 4) return;
    int s = s4 * 4;
    int rg = blockIdx.y;                       // b*L + l
    int b = rg / L_;

    float rm = rowM[rg], rrz = rowRZ[rg], okl = oklA[rg];

    f32x4 vv = __builtin_nontemporal_load((const f32x4*)(sim + (size_t)rg * S_ + s));
    int cb = b * S_ + s;
    f32x4 cmv = *(const f32x4*)(colM + cb);
    f32x4 crz = *(const f32x4*)(colRZ + cb);
    f32x4 oks = *(const f32x4*)(oksA + cb);

    f32x4 o0, o1, o2;
#pragma unroll
    for (int i = 0; i < 4; ++i) {
        float v = vv[i];
        float e = exp2f(v * kLOG2E);
        float c0v = e * rrz;
        float c1v = e * crz[i];
        bool mk = ((c0v > 0.2f) & (v == rm)) | ((c1v > 0.2f) & (v == cmv[i]));
        o0[i] = c0v;
        o1[i] = c1v;
        o2[i] = mk ? fmaxf(c0v, c1v) * okl * oks[i] : 0.f;
    }

    size_t o = (size_t)rg * S_ + s;
    __builtin_nontemporal_store(o0, (f32x4*)(out + o));
    __builtin_nontemporal_store(o1, (f32x4*)(out + o + BLS));
    __builtin_nontemporal_store(o2, (f32x4*)(out + o + 2 * BLS));
}

extern "C" void kernel_launch(void* const* d_in, const int* in_sizes, int n_in,
                              void* d_out, int out_size, void* d_ws, size_t ws_size,
                              hipStream_t stream) {
    const float* feat0 = (const float*)d_in[0];
    const float* feat1 = (const float*)d_in[1];
    const float* W = (const float*)d_in[2];
    const float* bias = (const float*)d_in[3];
    const int* ph0 = (const int*)d_in[4];
    const int* pw0 = (const int*)d_in[5];
    const int* ph1 = (const int*)d_in[6];
    const int* pw1 = (const int*)d_in[7];
    float* out = (float*)d_out;

    char* ws = (char*)d_ws;
    size_t off = 0;
    auto alloc = [&](size_t bytes) { char* p = ws + off; off = (off + bytes + 255) & ~(size_t)255; return p; };
    __hip_bfloat16* f0 = (__hip_bfloat16*)alloc((size_t)B_ * L_ * C_ * 2);
    __hip_bfloat16* f1 = (__hip_bfloat16*)alloc((size_t)B_ * S_ * C_ * 2);
    float* sim = (float*)alloc(BLS * 4);
    float* rowPM = (float*)alloc((size_t)NT2_ * BL_ * 4);
    float* rowPZ = (float*)alloc((size_t)NT2_ * BL_ * 4);
    float* colPM = (float*)alloc((size_t)NT2_ * BS_ * 4);
    float* colPZ = (float*)alloc((size_t)NT2_ * BS_ * 4);
    float* rowM = (float*)alloc((size_t)BL_ * 4);
    float* rowRZ = (float*)alloc((size_t)BL_ * 4);
    float* oklA = (float*)alloc((size_t)BL_ * 4);
    float* colM = (float*)alloc((size_t)BS_ * 4);
    float* colRZ = (float*)alloc((size_t)BS_ * 4);
    float* oksA = (float*)alloc((size_t)BS_ * 4);
    (void)ws_size; (void)in_sizes; (void)n_in; (void)out_size;

    proj_kernel<<<dim3(150, 16, 2), 256, 0, stream>>>(feat0, feat1, W, bias, f0, f1);
    simstat_kernel<<<dim3(NT2_, NT2_, B_), 256, 0, stream>>>(f0, f1, sim, rowPM, rowPZ, colPM, colPZ);
    stats_reduce_kernel<<<dim3(75), 256, 0, stream>>>(rowPM, rowPZ, colPM, colPZ,
                                                      ph0, pw0, ph1, pw1,
                                                      rowM, rowRZ, oklA, colM, colRZ, oksA);
    final_kernel<<<dim3(5, BL_), 256, 0, stream>>>(sim, rowM, rowRZ, oklA,
                                                   colM, colRZ, oksA, out);
}

// Round 5
// 756.321 us; speedup vs baseline: 1.3547x; 1.0393x over previous
//
#include <hip/hip_runtime.h>
#include <hip/hip_bf16.h>

#define B_ 2
#define L_ 4800
#define S_ 4800
#define C_ 256
#define NTR_ 50                     // 4800 / 96  row tiles
#define NTC_ 25                     // 4800 / 192 col tiles
#define BL_ (B_ * L_)               // 9600
#define BS_ (B_ * S_)               // 9600
#define BLS ((size_t)B_ * L_ * S_)

constexpr float kLOG2E = 1.4426950408889634f;

typedef __bf16 bf16x8 __attribute__((ext_vector_type(8)));
typedef float f32x4 __attribute__((ext_vector_type(4)));

static __device__ __forceinline__ f32x4 mfma16(bf16x8 a, bf16x8 b, f32x4 c) {
    return __builtin_amdgcn_mfma_f32_16x16x32_bf16(a, b, c, 0, 0, 0);
}

// load 8 contiguous fp32, round-to-nearest-even convert to bf16x8
static __device__ __forceinline__ bf16x8 load_cvt8(const float* __restrict__ p) {
    float4 a = *(const float4*)p;
    float4 b = *(const float4*)(p + 4);
    bf16x8 r;
    r[0] = (__bf16)a.x; r[1] = (__bf16)a.y; r[2] = (__bf16)a.z; r[3] = (__bf16)a.w;
    r[4] = (__bf16)b.x; r[5] = (__bf16)b.y; r[6] = (__bf16)b.z; r[7] = (__bf16)b.w;
    return r;
}

// ---------------- K1: projection f = (x @ W^T + bias) / 16, bf16 out ----------------
// UNCHANGED from passing version.
__global__ __launch_bounds__(256) void proj_kernel(
    const float* __restrict__ x0, const float* __restrict__ x1,
    const float* __restrict__ W, const float* __restrict__ bias,
    __hip_bfloat16* __restrict__ y0, __hip_bfloat16* __restrict__ y1) {
    const float* __restrict__ x = (blockIdx.z == 0) ? x0 : x1;
    __hip_bfloat16* __restrict__ y = (blockIdx.z == 0) ? y0 : y1;

    int lane = threadIdx.x & 63, wid = threadIdx.x >> 6;
    int m = lane & 15, q = lane >> 4;
    int r0 = blockIdx.x * 64 + wid * 16;
    int c0 = blockIdx.y * 16;

    f32x4 acc = {0.f, 0.f, 0.f, 0.f};
    for (int kk = 0; kk < 8; ++kk) {
        bf16x8 a = load_cvt8(x + (size_t)(r0 + m) * C_ + kk * 32 + q * 8);
        bf16x8 b = load_cvt8(W + (size_t)(c0 + m) * C_ + kk * 32 + q * 8);
        acc = mfma16(a, b, acc);
    }
    float bv = bias[c0 + m];
#pragma unroll
    for (int i = 0; i < 4; ++i) {
        int row = q * 4 + i;  // C/D mapping: col = lane&15, row = (lane>>4)*4 + i
        y[(size_t)(r0 + row) * C_ + c0 + m] = __float2bfloat16((acc[i] + bv) * 0.0625f);
    }
}

// ---------------- K2: 96x192-tile GEMM + sim write (fp32, CACHEABLE) + per-tile stats ----
// grid (50, 25, 2), block 256 = 4 waves in 2(wm)x2(wn); each wave 48x96 = 3x6 frags.
// 18 MFMA : 9 loads per k-step (2:1). Epilogue processes fragments transiently
// (no v/e register arrays). sim stores are cacheable so K4 can hit L3.
__global__ __launch_bounds__(256) void simstat_kernel(
    const __hip_bfloat16* __restrict__ f0, const __hip_bfloat16* __restrict__ f1,
    float* __restrict__ sim,
    float* __restrict__ rowPM, float* __restrict__ rowPZ,
    float* __restrict__ colPM, float* __restrict__ colPZ) {
    int b = blockIdx.z;
    int lane = threadIdx.x & 63, wid = threadIdx.x >> 6;
    int wm = wid & 1, wn = wid >> 1;
    int mi = lane & 15, q = lane >> 4;
    int r0 = blockIdx.x * 96 + wm * 48;
    int c0 = blockIdx.y * 192 + wn * 96;

    const __hip_bfloat16* __restrict__ A = f0 + (size_t)b * L_ * C_;
    const __hip_bfloat16* __restrict__ Bp = f1 + (size_t)b * S_ * C_;

    f32x4 acc[3][6] = {};
#pragma unroll
    for (int kk = 0; kk < 8; ++kk) {
        int ko = kk * 32 + q * 8;
        bf16x8 af[3], bf[6];
#pragma unroll
        for (int m = 0; m < 3; ++m)
            af[m] = *(const bf16x8*)(A + (size_t)(r0 + m * 16 + mi) * C_ + ko);
#pragma unroll
        for (int n = 0; n < 6; ++n)
            bf[n] = *(const bf16x8*)(Bp + (size_t)(c0 + n * 16 + mi) * C_ + ko);
#pragma unroll
        for (int m = 0; m < 3; ++m)
#pragma unroll
            for (int n = 0; n < 6; ++n)
                acc[m][n] = mfma16(af[m], bf[n], acc[m][n]);
    }

    float* __restrict__ simb = sim + (size_t)b * L_ * S_;

    // running stats; fragments processed transiently
    float rm[3][4], rz[3][4];           // row (m,i,q) owner, reduce over mi later
#pragma unroll
    for (int m = 0; m < 3; ++m)
#pragma unroll
        for (int i = 0; i < 4; ++i) { rm[m][i] = -3.0e38f; rz[m][i] = 0.f; }
    float cm[6], cz[6];                 // col (n,mi) owner, reduce over q later
#pragma unroll
    for (int n = 0; n < 6; ++n) { cm[n] = -3.0e38f; cz[n] = 0.f; }

#pragma unroll
    for (int n = 0; n < 6; ++n) {
#pragma unroll
        for (int m = 0; m < 3; ++m)
#pragma unroll
            for (int i = 0; i < 4; ++i) {
                float x = acc[m][n][i] * 10.0f;
                float e = exp2f(x * kLOG2E);
                size_t o = (size_t)(r0 + m * 16 + q * 4 + i) * S_ + c0 + n * 16 + mi;
                simb[o] = x;                       // cacheable: K4 re-reads via L3
                rm[m][i] = fmaxf(rm[m][i], x); rz[m][i] += e;
                cm[n] = fmaxf(cm[n], x);       cz[n] += e;
            }
    }

    // row reduce over mi (xor 1,2,4,8)
#pragma unroll
    for (int m = 0; m < 3; ++m)
#pragma unroll
        for (int i = 0; i < 4; ++i) {
#pragma unroll
            for (int d = 1; d < 16; d <<= 1) {
                rm[m][i] = fmaxf(rm[m][i], __shfl_xor(rm[m][i], d));
                rz[m][i] += __shfl_xor(rz[m][i], d);
            }
        }
    // col reduce over q (xor 16,32)
#pragma unroll
    for (int n = 0; n < 6; ++n) {
#pragma unroll
        for (int d = 16; d < 64; d <<= 1) {
            cm[n] = fmaxf(cm[n], __shfl_xor(cm[n], d));
            cz[n] += __shfl_xor(cz[n], d);
        }
    }

    // combine across waves: rows merge over wn, cols merge over wm
    __shared__ float lRM[2][96], lRZ[2][96], lCM[2][192], lCZ[2][192];
    if (mi == 0) {
#pragma unroll
        for (int m = 0; m < 3; ++m)
#pragma unroll
            for (int i = 0; i < 4; ++i) {
                int rl = wm * 48 + m * 16 + q * 4 + i;
                lRM[wn][rl] = rm[m][i];
                lRZ[wn][rl] = rz[m][i];
            }
    }
    if (q == 0) {
#pragma unroll
        for (int n = 0; n < 6; ++n) {
            int cl = wn * 96 + n * 16 + mi;
            lCM[wm][cl] = cm[n];
            lCZ[wm][cl] = cz[n];
        }
    }
    __syncthreads();

    int t = threadIdx.x;
    if (t < 96) {
        float m = fmaxf(lRM[0][t], lRM[1][t]);
        float z = lRZ[0][t] + lRZ[1][t];
        size_t o = (size_t)blockIdx.y * BL_ + (size_t)b * L_ + blockIdx.x * 96 + t;
        rowPM[o] = m; rowPZ[o] = z;
    }
    if (t < 192) {
        float m = fmaxf(lCM[0][t], lCM[1][t]);
        float z = lCZ[0][t] + lCZ[1][t];
        size_t o = (size_t)blockIdx.x * BS_ + (size_t)b * S_ + blockIdx.y * 192 + t;
        colPM[o] = m; colPZ[o] = z;
    }
}

// ---------------- K3: reduce partials (rows: 25, cols: 50); reciprocals; masks ----------
// grid 75 blocks x 256 = 19200 threads: [0,9600) rows, [9600,19200) cols.
__global__ __launch_bounds__(256) void stats_reduce_kernel(
    const float* __restrict__ rowPM, const float* __restrict__ rowPZ,
    const float* __restrict__ colPM, const float* __restrict__ colPZ,
    const int* __restrict__ ph0, const int* __restrict__ pw0,
    const int* __restrict__ ph1, const int* __restrict__ pw1,
    float* __restrict__ rowM, float* __restrict__ rowRZ, float* __restrict__ oklA,
    float* __restrict__ colM, float* __restrict__ colRZ, float* __restrict__ oksA) {
    int idx = blockIdx.x * 256 + threadIdx.x;
    if (idx < BL_) {
        float m = -3.0e38f, z = 0.f;
        for (int j = 0; j < NTC_; ++j) {
            m = fmaxf(m, rowPM[(size_t)j * BL_ + idx]);
            z += rowPZ[(size_t)j * BL_ + idx];
        }
        rowM[idx] = m;
        rowRZ[idx] = 1.0f / z;
        int l = idx % L_;
        int h0 = ph0[0], w0 = pw0[0];
        int i0 = l / w0, j0 = l - i0 * w0;
        oklA[idx] = ((i0 >= 2) & (i0 < h0 - 2) & (j0 >= 2) & (j0 < w0 - 2)) ? 1.f : 0.f;
    } else if (idx < BL_ + BS_) {
        int c = idx - BL_;
        float m = -3.0e38f, z = 0.f;
        for (int j = 0; j < NTR_; ++j) {
            m = fmaxf(m, colPM[(size_t)j * BS_ + c]);
            z += colPZ[(size_t)j * BS_ + c];
        }
        colM[c] = m;
        colRZ[c] = 1.0f / z;
        int s = c % S_;
        int h1 = ph1[0], w1 = pw1[0];
        int i1 = s / w1, j1 = s - i1 * w1;
        oksA[c] = ((i1 >= 2) & (i1 < h1 - 2) & (j1 >= 2) & (j1 < w1 - 2)) ? 1.f : 0.f;
    }
}

// ---------------- K4: pure streaming final. grid (5, 9600), block 256 ----------------
// Regular (cacheable) load of sim -> L3 hits; nontemporal stores for out only.
__global__ __launch_bounds__(256) void final_kernel(
    const float* __restrict__ sim,
    const float* __restrict__ rowM, const float* __restrict__ rowRZ, const float* __restrict__ oklA,
    const float* __restrict__ colM, const float* __restrict__ colRZ, const float* __restrict__ oksA,
    float* __restrict__ out) {
    int s4 = blockIdx.x * 256 + threadIdx.x;   // float4 index within a row
    if (s4 >= S_ / 4) return;
    int s = s4 * 4;
    int rg = blockIdx.y;                       // b*L + l
    int b = rg / L_;

    float rm = rowM[rg], rrz = rowRZ[rg], okl = oklA[rg];

    f32x4 vv = *(const f32x4*)(sim + (size_t)rg * S_ + s);
    int cb = b * S_ + s;
    f32x4 cmv = *(const f32x4*)(colM + cb);
    f32x4 crz = *(const f32x4*)(colRZ + cb);
    f32x4 oks = *(const f32x4*)(oksA + cb);

    f32x4 o0, o1, o2;
#pragma unroll
    for (int i = 0; i < 4; ++i) {
        float v = vv[i];
        float e = exp2f(v * kLOG2E);
        float c0v = e * rrz;
        float c1v = e * crz[i];
        bool mk = ((c0v > 0.2f) & (v == rm)) | ((c1v > 0.2f) & (v == cmv[i]));
        o0[i] = c0v;
        o1[i] = c1v;
        o2[i] = mk ? fmaxf(c0v, c1v) * okl * oks[i] : 0.f;
    }

    size_t o = (size_t)rg * S_ + s;
    __builtin_nontemporal_store(o0, (f32x4*)(out + o));
    __builtin_nontemporal_store(o1, (f32x4*)(out + o + BLS));
    __builtin_nontemporal_store(o2, (f32x4*)(out + o + 2 * BLS));
}

extern "C" void kernel_launch(void* const* d_in, const int* in_sizes, int n_in,
                              void* d_out, int out_size, void* d_ws, size_t ws_size,
                              hipStream_t stream) {
    const float* feat0 = (const float*)d_in[0];
    const float* feat1 = (const float*)d_in[1];
    const float* W = (const float*)d_in[2];
    const float* bias = (const float*)d_in[3];
    const int* ph0 = (const int*)d_in[4];
    const int* pw0 = (const int*)d_in[5];
    const int* ph1 = (const int*)d_in[6];
    const int* pw1 = (const int*)d_in[7];
    float* out = (float*)d_out;

    char* ws = (char*)d_ws;
    size_t off = 0;
    auto alloc = [&](size_t bytes) { char* p = ws + off; off = (off + bytes + 255) & ~(size_t)255; return p; };
    __hip_bfloat16* f0 = (__hip_bfloat16*)alloc((size_t)B_ * L_ * C_ * 2);
    __hip_bfloat16* f1 = (__hip_bfloat16*)alloc((size_t)B_ * S_ * C_ * 2);
    float* sim = (float*)alloc(BLS * 4);
    float* rowPM = (float*)alloc((size_t)NTC_ * BL_ * 4);
    float* rowPZ = (float*)alloc((size_t)NTC_ * BL_ * 4);
    float* colPM = (float*)alloc((size_t)NTR_ * BS_ * 4);
    float* colPZ = (float*)alloc((size_t)NTR_ * BS_ * 4);
    float* rowM = (float*)alloc((size_t)BL_ * 4);
    float* rowRZ = (float*)alloc((size_t)BL_ * 4);
    float* oklA = (float*)alloc((size_t)BL_ * 4);
    float* colM = (float*)alloc((size_t)BS_ * 4);
    float* colRZ = (float*)alloc((size_t)BS_ * 4);
    float* oksA = (float*)alloc((size_t)BS_ * 4);
    (void)ws_size; (void)in_sizes; (void)n_in; (void)out_size;

    proj_kernel<<<dim3(150, 16, 2), 256, 0, stream>>>(feat0, feat1, W, bias, f0, f1);
    simstat_kernel<<<dim3(NTR_, NTC_, B_), 256, 0, stream>>>(f0, f1, sim, rowPM, rowPZ, colPM, colPZ);
    stats_reduce_kernel<<<dim3(75), 256, 0, stream>>>(rowPM, rowPZ, colPM, colPZ,
                                                      ph0, pw0, ph1, pw1,
                                                      rowM, rowRZ, oklA, colM, colRZ, oksA);
    final_kernel<<<dim3(5, BL_), 256, 0, stream>>>(sim, rowM, rowRZ, oklA,
                                                   colM, colRZ, oksA, out);
}